// Round 7
// baseline (1604.610 us; speedup 1.0000x reference)
//
#include <hip/hip_runtime.h>
#include <math.h>

#define DIM 16384
#define NTH 512
#define NBLK 256

typedef float v2f __attribute__((ext_vector_type(2)));

// amp index i lives at LDS/global slot cswz(i); XOR-linear involution (bank-fold).
__host__ __device__ constexpr int cswz(int i) {
  return i ^ ((i >> 4) & 15) ^ ((i >> 8) & 15) ^ ((i >> 12) & 3);
}

// 10 passes per layer; 4 wires per window (local bit b <-> wire LWp[p][b])
constexpr int LWp[10][4] = {
  {13, 0, 12, 11},   // P0: RY{13,0,12,11}+CRX(13,0)(12,13)(11,12)
  {10, 9, 8, 11},    // P1: RY{10,9,8}+CRX(10,11)(9,10)(8,9)
  {7, 6, 5, 8},      // P2: RY{7,6,5}+CRX(7,8)(6,7)(5,6)
  {4, 3, 2, 5},      // P3: RY{4,3,2}+CRX(4,5)(3,4)(2,3)
  {1, 0, 2, 3},      // P4: RY{1}+CRX(1,2)(0,1)
  {13, 12, 0, 1},    // P5: RY{13,12,0,1}+CRX(13,12)(0,13)(1,0)
  {2, 1, 3, 4},      // P6: RY{2,3,4}+CRX(2,1)(3,2)(4,3)
  {5, 4, 6, 7},      // P7: RY{5,6,7}+CRX(5,4)(6,5)(7,6)
  {8, 7, 9, 10},     // P8: RY{8,9,10}+CRX(8,7)(9,8)(10,9)
  {11, 10, 12, 9},   // P9: RY{11}+CRX(11,10)(12,11)
};
// tid bit k (k=0..8) -> bit position PM[p][k]; subcube-half bit h -> PM[p][9]
constexpr int PM[10][10] = {
  {3, 4, 5, 6, 7, 8, 9, 10, 11, 12},
  {0, 1, 6, 7, 8, 9, 10, 11, 12, 13},
  {0, 1, 2, 3, 4, 9, 10, 11, 12, 13},
  {0, 1, 2, 3, 4, 5, 6, 7, 12, 13},
  {0, 1, 2, 3, 4, 5, 6, 7, 8, 9},
  {2, 3, 4, 5, 6, 7, 8, 9, 10, 11},
  {0, 1, 2, 3, 4, 5, 6, 7, 8, 13},
  {0, 1, 2, 3, 4, 5, 10, 11, 12, 13},
  {0, 1, 2, 7, 8, 9, 10, 11, 12, 13},
  {0, 5, 6, 7, 8, 9, 10, 11, 12, 13},
};
constexpr int NGp[10] = {7, 6, 6, 6, 3, 7, 6, 6, 6, 3};
// {kind(0=RY,1=CRX), localA(RY tgt / CRX ctrl), localB(CRX tgt), cs idx (layer-rel)}
constexpr int GT[10][7][4] = {
  {{0,0,0,13},{0,1,0,0},{0,2,0,12},{0,3,0,11},{1,0,1,14},{1,2,0,15},{1,3,2,16}},
  {{0,0,0,10},{0,1,0,9},{0,2,0,8},{1,0,3,17},{1,1,0,18},{1,2,1,19},{0,0,0,0}},
  {{0,0,0,7},{0,1,0,6},{0,2,0,5},{1,0,3,20},{1,1,0,21},{1,2,1,22},{0,0,0,0}},
  {{0,0,0,4},{0,1,0,3},{0,2,0,2},{1,0,3,23},{1,1,0,24},{1,2,1,25},{0,0,0,0}},
  {{0,0,0,1},{1,0,2,26},{1,1,0,27},{0,0,0,0},{0,0,0,0},{0,0,0,0},{0,0,0,0}},
  {{0,0,0,41},{0,1,0,40},{0,2,0,28},{0,3,0,29},{1,0,1,42},{1,2,0,43},{1,3,2,44}},
  {{0,0,0,30},{0,2,0,31},{0,3,0,32},{1,0,1,45},{1,2,0,46},{1,3,2,47},{0,0,0,0}},
  {{0,0,0,33},{0,2,0,34},{0,3,0,35},{1,0,1,48},{1,2,0,49},{1,3,2,50},{0,0,0,0}},
  {{0,0,0,36},{0,2,0,37},{0,3,0,38},{1,0,1,51},{1,2,0,52},{1,3,2,53},{0,0,0,0}},
  {{0,0,0,39},{1,0,1,54},{1,2,0,55},{0,0,0,0},{0,0,0,0},{0,0,0,0},{0,0,0,0}},
};

__host__ __device__ constexpr int offcube4(int p, int j) {
  int o = 0;
  for (int b = 0; b < 4; ++b)
    if ((j >> b) & 1) o |= 1 << (13 - LWp[p][b]);
  return o;
}

template <int PID>
__device__ __forceinline__ int sub_slot(int tid, int h) {
  int base = h << PM[PID][9];
#pragma unroll
  for (int k = 0; k < 9; ++k) base |= ((tid >> k) & 1) << PM[PID][k];
  return cswz(base);
}

template <int PID>
__device__ __forceinline__ void gates16(const v2f* __restrict__ CS, v2f* __restrict__ a) {
#pragma unroll
  for (int g = 0; g < NGp[PID]; ++g) {
    const v2f cs2 = CS[GT[PID][g][3]];
    const float c = cs2.x, s = cs2.y;
    if (GT[PID][g][0] == 0) {
      const int tb = GT[PID][g][1];
#pragma unroll
      for (int j = 0; j < 16; ++j)
        if (!((j >> tb) & 1)) {
          const int j2 = j | (1 << tb);
          const v2f a0 = a[j], a1 = a[j2];
          a[j]  = c * a0 - s * a1;
          a[j2] = s * a0 + c * a1;
        }
    } else {
      const int bc = GT[PID][g][1], bt = GT[PID][g][2];
#pragma unroll
      for (int j = 0; j < 16; ++j)
        if (((j >> bc) & 1) && !((j >> bt) & 1)) {
          const int j2 = j | (1 << bt);
          const v2f t0 = a[j], t1 = a[j2];
          a[j]  = c * t0 + s * v2f{t1.y, -t1.x};
          a[j2] = c * t1 + s * v2f{t0.y, -t0.x};
        }
    }
  }
}

// MODE: 0 = gather+gates+scatter, 1 = zero-init(|0>)+gates+scatter, 2 = gather+gates+accumulate
template <int PID, int MODE>
__device__ __forceinline__ void pass2(v2f* __restrict__ S, const v2f* __restrict__ CS,
                                      int tid, v2f* __restrict__ acc, float mc) {
#pragma unroll
  for (int h = 0; h < 2; ++h) {
    const int sb = sub_slot<PID>(tid, h);
    v2f a[16];
    if (MODE == 1) {
#pragma unroll
      for (int j = 0; j < 16; ++j) a[j] = v2f{0.f, 0.f};
      if (tid == 0 && h == 0) a[0] = v2f{1.f, 0.f};
    } else {
#pragma unroll
      for (int j = 0; j < 16; ++j) a[j] = S[sb ^ cswz(offcube4(PID, j))];
    }
    gates16<PID>(CS, a);
    if (MODE == 2) {
#pragma unroll
      for (int j = 0; j < 16; ++j) acc[h * 16 + j] += mc * a[j];
    } else {
#pragma unroll
      for (int j = 0; j < 16; ++j) S[sb ^ cswz(offcube4(PID, j))] = a[j];
    }
  }
  __syncthreads();
}

// one 112-gate sim reading state from S (or |0> if INITZERO); acc += mc * U(state)
template <bool INITZERO>
__device__ __forceinline__ void run_sim(v2f* __restrict__ S, const v2f* __restrict__ CS,
                                        int tid, v2f* __restrict__ acc, float mc) {
  if (INITZERO) pass2<0, 1>(S, CS, tid, acc, 0.f);
  else          pass2<0, 0>(S, CS, tid, acc, 0.f);
  pass2<1, 0>(S, CS, tid, acc, 0.f);
  pass2<2, 0>(S, CS, tid, acc, 0.f);
  pass2<3, 0>(S, CS, tid, acc, 0.f);
  pass2<4, 0>(S, CS, tid, acc, 0.f);
  pass2<5, 0>(S, CS, tid, acc, 0.f);
  pass2<6, 0>(S, CS, tid, acc, 0.f);
  pass2<7, 0>(S, CS, tid, acc, 0.f);
  pass2<8, 0>(S, CS, tid, acc, 0.f);
  pass2<9, 0>(S, CS, tid, acc, 0.f);
  const v2f* C2 = CS + 56;
  pass2<0, 0>(S, C2, tid, acc, 0.f);
  pass2<1, 0>(S, C2, tid, acc, 0.f);
  pass2<2, 0>(S, C2, tid, acc, 0.f);
  pass2<3, 0>(S, C2, tid, acc, 0.f);
  pass2<4, 0>(S, C2, tid, acc, 0.f);
  pass2<5, 0>(S, C2, tid, acc, 0.f);
  pass2<6, 0>(S, C2, tid, acc, 0.f);
  pass2<7, 0>(S, C2, tid, acc, 0.f);
  pass2<8, 0>(S, C2, tid, acc, 0.f);
  pass2<9, 2>(S, C2, tid, acc, mc);   // final pass: accumulate, no scatter
}

// scatter acc -> S (P9 ownership) then linear-copy S -> g (coalesced)
__device__ __forceinline__ void export_state(v2f* __restrict__ S, v2f* __restrict__ g,
                                             int tid, const v2f* __restrict__ acc) {
#pragma unroll
  for (int h = 0; h < 2; ++h) {
    const int sb = sub_slot<9>(tid, h);
#pragma unroll
    for (int j = 0; j < 16; ++j) S[sb ^ cswz(offcube4(9, j))] = acc[h * 16 + j];
  }
  __syncthreads();
#pragma unroll
  for (int j = 0; j < 32; ++j) { const int s = tid + j * NTH; g[s] = S[s]; }
  __syncthreads();
}

__device__ __forceinline__ float block_sum(float v, int tid, float* red) {
#pragma unroll
  for (int off = 32; off; off >>= 1) v += __shfl_xor(v, off);
  if ((tid & 63) == 0) red[tid >> 6] = v;
  __syncthreads();
  float tot = 0.f;
#pragma unroll
  for (int w = 0; w < 8; ++w) tot += red[w];
  __syncthreads();
  return tot;
}

__global__ __launch_bounds__(NTH, 1) void qts_kernel(
    const float* __restrict__ x, const float* __restrict__ Win,
    const float* __restrict__ bin, const float* __restrict__ mix,
    const float* __restrict__ poly, const float* __restrict__ Wout,
    const float* __restrict__ bout, float* __restrict__ out,
    v2f* __restrict__ gAall, v2f* __restrict__ gBall) {
  __shared__ v2f S[DIM + 448 + 128];
  v2f* CSall = S + DIM;
  float* red = (float*)(S + DIM + 448);
  const int tid = threadIdx.x;
  const int b = blockIdx.x;
  v2f* gA = gAall + (size_t)b * DIM;
  v2f* gB = gBall + (size_t)b * DIM;

  // angles for all 4 timesteps: theta = sigmoid(x@Win+bin); store (cos,sin)(theta/2)
  if (tid < 448) {
    float z = bin[tid];
    const float x0 = x[b * 4 + 0], x1 = x[b * 4 + 1], x2 = x[b * 4 + 2], x3 = x[b * 4 + 3];
    z += x0 * Win[tid] + x1 * Win[448 + tid] + x2 * Win[896 + tid] + x3 * Win[1344 + tid];
    const float th = 1.f / (1.f + expf(-z));
    float sn, cc;
    sincosf(0.5f * th, &sn, &cc);
    CSall[tid] = v2f{cc, sn};
  }
  __syncthreads();

  const float p0 = poly[0], p1 = poly[1], p2 = poly[2];
  v2f acc[32];

  // ---- v1 = M(|0>) ----
#pragma unroll
  for (int j = 0; j < 32; ++j) acc[j] = v2f{0.f, 0.f};
  for (int t = 0; t < 4; ++t)
    run_sim<true>(S, CSall + t * 112, tid, acc, mix[t]);
  float n1;
  {
    float part = 0.f;
#pragma unroll
    for (int j = 0; j < 32; ++j) part += acc[j].x * acc[j].x + acc[j].y * acc[j].y;
    n1 = sqrtf(block_sum(part, tid, red));
  }
  export_state(S, gA, tid, acc);       // S now holds v1 (slot layout)

  // ---- v2 = M(v1) ----
#pragma unroll
  for (int j = 0; j < 32; ++j) acc[j] = v2f{0.f, 0.f};
  for (int t = 0; t < 4; ++t) {
    if (t) {
#pragma unroll
      for (int j = 0; j < 32; ++j) { const int s = tid + j * NTH; S[s] = gA[s]; }
      __syncthreads();
    }
    run_sim<false>(S, CSall + t * 112, tid, acc, mix[t]);
  }
  float n2;
  {
    float part = 0.f;
#pragma unroll
    for (int j = 0; j < 32; ++j) part += acc[j].x * acc[j].x + acc[j].y * acc[j].y;
    n2 = sqrtf(block_sum(part, tid, red));
  }
  export_state(S, gB, tid, acc);       // S now holds v2

  // ---- v3 = M(v2) ----
#pragma unroll
  for (int j = 0; j < 32; ++j) acc[j] = v2f{0.f, 0.f};
  for (int t = 0; t < 4; ++t) {
    if (t) {
#pragma unroll
      for (int j = 0; j < 32; ++j) { const int s = tid + j * NTH; S[s] = gB[s]; }
      __syncthreads();
    }
    run_sim<false>(S, CSall + t * 112, tid, acc, mix[t]);
  }
  // scatter v3 -> S for the linear final phase
#pragma unroll
  for (int h = 0; h < 2; ++h) {
    const int sb = sub_slot<9>(tid, h);
#pragma unroll
    for (int j = 0; j < 16; ++j) S[sb ^ cswz(offcube4(9, j))] = acc[h * 16 + j];
  }
  __syncthreads();

  // ---- res = p0*v1 + p1/(n1+e)*v2 + p2/(n2+e*(n1+e))*v3 ; expz + norm ; GEMV ----
  const float n1e = n1 + 1e-9f;
  const float n2e = n2 + 1e-9f * n1e;
  const float c2 = p1 / n1e;
  const float c3 = p2 / n2e;
  float part[15];
#pragma unroll
  for (int v = 0; v < 15; ++v) part[v] = 0.f;
#pragma unroll
  for (int j = 0; j < 32; ++j) {
    const int s = tid + j * NTH;
    const int i = cswz(s);               // amp index at slot s
    const v2f r = p0 * gA[s] + c2 * gB[s] + c3 * S[s];
    const float p = r.x * r.x + r.y * r.y;
    part[14] += p;
#pragma unroll
    for (int w = 0; w < 14; ++w) part[w] += ((i >> (13 - w)) & 1) ? -p : p;
  }
  __syncthreads();
#pragma unroll
  for (int v = 0; v < 15; ++v) {
    float xv = part[v];
#pragma unroll
    for (int off = 32; off; off >>= 1) xv += __shfl_xor(xv, off);
    if ((tid & 63) == 0) red[(tid >> 6) * 15 + v] = xv;
  }
  __syncthreads();
  if (tid < 15) {
    float tot = 0.f;
#pragma unroll
    for (int w = 0; w < 8; ++w) tot += red[w * 15 + tid];
    red[128 + tid] = tot;
  }
  __syncthreads();
  if (tid < 2) {
    const float nrm = sqrtf(red[128 + 14]) + 1e-9f;
    const float iv = 1.f / (nrm * nrm);
    float o = bout[tid];
#pragma unroll
    for (int w = 0; w < 14; ++w) o += red[128 + w] * iv * Wout[w * 2 + tid];
    out[b * 2 + tid] = o;
  }
}

// ================= fallback (verified round-6 kernel) for small ws =================
constexpr int LW[8][5] = {
  {13, 12, 11, 10, 0}, {10, 9, 8, 7, 6}, {6, 5, 4, 3, 2}, {2, 1, 0, 3, 4},
  {12, 13, 0, 1, 2}, {2, 3, 4, 5, 6}, {6, 7, 8, 9, 10}, {10, 11, 12, 13, 9},
};
constexpr int PMAP[8][9] = {
  {4, 5, 6, 7, 8, 9, 10, 11, 12}, {0, 1, 2, 11, 8, 9, 10, 12, 13},
  {0, 1, 2, 3, 4, 5, 6, 12, 13}, {0, 1, 2, 3, 4, 5, 6, 7, 8},
  {2, 3, 4, 5, 6, 7, 8, 9, 10}, {0, 1, 2, 3, 4, 5, 6, 12, 13},
  {0, 1, 2, 11, 8, 9, 10, 12, 13}, {5, 6, 7, 8, 9, 10, 11, 12, 13},
};
constexpr int NG[8] = {9, 8, 8, 3, 9, 8, 8, 3};
constexpr int GATES[8][9][4] = {
  {{0,4,0,0},{0,3,0,10},{0,2,0,11},{0,1,0,12},{0,0,0,13},{1,0,4,14},{1,1,0,15},{1,2,1,16},{1,3,2,17}},
  {{0,4,0,6},{0,3,0,7},{0,2,0,8},{0,1,0,9},{1,1,0,18},{1,2,1,19},{1,3,2,20},{1,4,3,21},{0,0,0,0}},
  {{0,4,0,2},{0,3,0,3},{0,2,0,4},{0,1,0,5},{1,1,0,22},{1,2,1,23},{1,3,2,24},{1,4,3,25},{0,0,0,0}},
  {{0,1,0,1},{1,1,0,26},{1,2,1,27},{0,0,0,0},{0,0,0,0},{0,0,0,0},{0,0,0,0},{0,0,0,0},{0,0,0,0}},
  {{0,2,0,28},{0,3,0,29},{0,4,0,30},{0,0,0,40},{0,1,0,41},{1,1,0,42},{1,2,1,43},{1,3,2,44},{1,4,3,45}},
  {{0,1,0,31},{0,2,0,32},{0,3,0,33},{0,4,0,34},{1,1,0,46},{1,2,1,47},{1,3,2,48},{1,4,3,49},{0,0,0,0}},
  {{0,1,0,35},{0,2,0,36},{0,3,0,37},{0,4,0,38},{1,1,0,50},{1,2,1,51},{1,3,2,52},{1,4,3,53},{0,0,0,0}},
  {{0,1,0,39},{1,1,0,54},{1,2,1,55},{0,0,0,0},{0,0,0,0},{0,0,0,0},{0,0,0,0},{0,0,0,0},{0,0,0,0}},
};
__host__ __device__ constexpr int offcube5(int p, int j) {
  int o = 0;
  for (int b = 0; b < 5; ++b)
    if ((j >> b) & 1) o |= 1 << (13 - LW[p][b]);
  return o;
}
template <int PID, int MODE>
__device__ __forceinline__ void fb_pass(v2f* __restrict__ S, const v2f* __restrict__ CS,
                                        int lb, int tid, v2f* __restrict__ a) {
  int base = 0;
#pragma unroll
  for (int k = 0; k < 9; ++k) base |= ((tid >> k) & 1) << PMAP[PID][k];
  const int sb = cswz(base);
  if (MODE == 1) {
#pragma unroll
    for (int j = 0; j < 32; ++j) a[j] = v2f{0.f, 0.f};
    if (tid == 0) a[0] = v2f{1.f, 0.f};
  } else {
#pragma unroll
    for (int j = 0; j < 32; ++j) a[j] = S[sb ^ cswz(offcube5(PID, j))];
  }
#pragma unroll
  for (int g = 0; g < NG[PID]; ++g) {
    const v2f cs2 = CS[lb + GATES[PID][g][3]];
    const float c = cs2.x, s = cs2.y;
    if (GATES[PID][g][0] == 0) {
      const int tb = GATES[PID][g][1];
#pragma unroll
      for (int j = 0; j < 32; ++j)
        if (!((j >> tb) & 1)) {
          const int j2 = j | (1 << tb);
          const v2f a0 = a[j], a1 = a[j2];
          a[j]  = c * a0 - s * a1;
          a[j2] = s * a0 + c * a1;
        }
    } else {
      const int bc = GATES[PID][g][1], bt = GATES[PID][g][2];
#pragma unroll
      for (int j = 0; j < 32; ++j)
        if (((j >> bc) & 1) && !((j >> bt) & 1)) {
          const int j2 = j | (1 << bt);
          const v2f t0 = a[j], t1 = a[j2];
          a[j]  = c * t0 + s * v2f{t1.y, -t1.x};
          a[j2] = c * t1 + s * v2f{t0.y, -t0.x};
        }
    }
  }
  if (MODE != 2) {
#pragma unroll
    for (int j = 0; j < 32; ++j) S[sb ^ cswz(offcube5(PID, j))] = a[j];
  }
  __syncthreads();
}
__device__ __forceinline__ void fb_sim(v2f* __restrict__ S, const v2f* __restrict__ CS,
                                       int tid, v2f* __restrict__ a,
                                       const v2f* __restrict__ basev, int own_sb,
                                       bool initzero) {
  if (initzero) {
    fb_pass<0, 1>(S, CS, 0, tid, a);
  } else {
#pragma unroll
    for (int j = 0; j < 32; ++j) S[own_sb ^ cswz(offcube5(7, j))] = basev[j];
    __syncthreads();
    fb_pass<0, 0>(S, CS, 0, tid, a);
  }
  fb_pass<1, 0>(S, CS, 0, tid, a);
  fb_pass<2, 0>(S, CS, 0, tid, a);
  fb_pass<3, 0>(S, CS, 0, tid, a);
  fb_pass<4, 0>(S, CS, 0, tid, a);
  fb_pass<5, 0>(S, CS, 0, tid, a);
  fb_pass<6, 0>(S, CS, 0, tid, a);
  fb_pass<7, 0>(S, CS, 0, tid, a);
  fb_pass<0, 0>(S, CS, 56, tid, a);
  fb_pass<1, 0>(S, CS, 56, tid, a);
  fb_pass<2, 0>(S, CS, 56, tid, a);
  fb_pass<3, 0>(S, CS, 56, tid, a);
  fb_pass<4, 0>(S, CS, 56, tid, a);
  fb_pass<5, 0>(S, CS, 56, tid, a);
  fb_pass<6, 0>(S, CS, 56, tid, a);
  fb_pass<7, 2>(S, CS, 56, tid, a);
}
__global__ __launch_bounds__(NTH, 1) void qts_fb(
    const float* __restrict__ x, const float* __restrict__ Win,
    const float* __restrict__ bin, const float* __restrict__ mix,
    const float* __restrict__ poly, const float* __restrict__ Wout,
    const float* __restrict__ bout, float* __restrict__ out) {
  __shared__ v2f S[DIM + 448 + 128];
  v2f* CSall = S + DIM;
  float* red = (float*)(S + DIM + 448);
  const int tid = threadIdx.x;
  const int b = blockIdx.x;
  if (tid < 448) {
    float z = bin[tid];
    const float x0 = x[b * 4 + 0], x1 = x[b * 4 + 1], x2 = x[b * 4 + 2], x3 = x[b * 4 + 3];
    z += x0 * Win[tid] + x1 * Win[448 + tid] + x2 * Win[896 + tid] + x3 * Win[1344 + tid];
    const float th = 1.f / (1.f + expf(-z));
    float sn, cc;
    sincosf(0.5f * th, &sn, &cc);
    CSall[tid] = v2f{cc, sn};
  }
  __syncthreads();
  int ownbase = 0;
#pragma unroll
  for (int k = 0; k < 9; ++k) ownbase |= ((tid >> k) & 1) << PMAP[7][k];
  const int own_sb = cswz(ownbase);
  const float p0 = poly[0], p1 = poly[1], p2 = poly[2];
  v2f a[32], acc[32], basev[32];
  float alpha;
#pragma unroll
  for (int j = 0; j < 32; ++j) acc[j] = v2f{0.f, 0.f};
  for (int t = 0; t < 4; ++t) {
    fb_sim(S, CSall + t * 112, tid, a, basev, own_sb, true);
    const float mc = mix[t];
#pragma unroll
    for (int j = 0; j < 32; ++j) acc[j] += mc * a[j];
  }
  {
    float part = 0.f;
#pragma unroll
    for (int j = 0; j < 32; ++j) part += acc[j].x * acc[j].x + acc[j].y * acc[j].y;
    const float tot = block_sum(part, tid, red);
    const float nu = sqrtf(tot) + 1e-9f;
    const float inv = 1.f / nu;
    alpha = p0 * nu;
#pragma unroll
    for (int j = 0; j < 32; ++j) { basev[j] = inv * acc[j]; acc[j] = v2f{0.f, 0.f}; }
  }
  for (int t = 0; t < 4; ++t) {
    fb_sim(S, CSall + t * 112, tid, a, basev, own_sb, false);
    const float mc = mix[t];
#pragma unroll
    for (int j = 0; j < 32; ++j) acc[j] += mc * a[j];
  }
  {
    float part = 0.f;
#pragma unroll
    for (int j = 0; j < 32; ++j) part += acc[j].x * acc[j].x + acc[j].y * acc[j].y;
    const float tot = block_sum(part, tid, red);
    const float nu = sqrtf(tot) + 1e-9f;
    const float inv = 1.f / nu;
#pragma unroll
    for (int j = 0; j < 32; ++j) {
      const v2f tmp = acc[j];
      acc[j] = alpha * basev[j] + p1 * tmp;
      basev[j] = inv * tmp;
    }
  }
  for (int t = 0; t < 4; ++t) {
    fb_sim(S, CSall + t * 112, tid, a, basev, own_sb, false);
    const float mc = p2 * mix[t];
#pragma unroll
    for (int j = 0; j < 32; ++j) acc[j] += mc * a[j];
  }
  float part[15];
#pragma unroll
  for (int v = 0; v < 15; ++v) part[v] = 0.f;
#pragma unroll
  for (int j = 0; j < 32; ++j) {
    const int idx = ownbase | offcube5(7, j);
    const float p = acc[j].x * acc[j].x + acc[j].y * acc[j].y;
    part[14] += p;
#pragma unroll
    for (int w = 0; w < 14; ++w) part[w] += ((idx >> (13 - w)) & 1) ? -p : p;
  }
  __syncthreads();
#pragma unroll
  for (int v = 0; v < 15; ++v) {
    float xv = part[v];
#pragma unroll
    for (int off = 32; off; off >>= 1) xv += __shfl_xor(xv, off);
    if ((tid & 63) == 0) red[(tid >> 6) * 15 + v] = xv;
  }
  __syncthreads();
  if (tid < 15) {
    float tot = 0.f;
#pragma unroll
    for (int w = 0; w < 8; ++w) tot += red[w * 15 + tid];
    red[128 + tid] = tot;
  }
  __syncthreads();
  if (tid < 2) {
    const float nrm = sqrtf(red[128 + 14]) + 1e-9f;
    const float iv = 1.f / (nrm * nrm);
    float o = bout[tid];
#pragma unroll
    for (int w = 0; w < 14; ++w) o += red[128 + w] * iv * Wout[w * 2 + tid];
    out[b * 2 + tid] = o;
  }
}

extern "C" void kernel_launch(void* const* d_in, const int* in_sizes, int n_in,
                              void* d_out, int out_size, void* d_ws, size_t ws_size,
                              hipStream_t stream) {
  const float* x    = (const float*)d_in[0];
  const float* Win  = (const float*)d_in[1];
  const float* bin  = (const float*)d_in[2];
  const float* mix  = (const float*)d_in[3];
  const float* poly = (const float*)d_in[4];
  const float* Wout = (const float*)d_in[5];
  const float* bout = (const float*)d_in[6];
  float* out = (float*)d_out;

  const size_t need = 2ull * NBLK * DIM * sizeof(float) * 2;  // 64 MB (v1 + v2 buffers)
  if (ws_size >= need) {
    v2f* gA = (v2f*)d_ws;
    v2f* gB = gA + (size_t)NBLK * DIM;
    qts_kernel<<<NBLK, NTH, 0, stream>>>(x, Win, bin, mix, poly, Wout, bout, out, gA, gB);
  } else {
    qts_fb<<<NBLK, NTH, 0, stream>>>(x, Win, bin, mix, poly, Wout, bout, out);
  }
}

// Round 8
// 1208.824 us; speedup vs baseline: 1.3274x; 1.3274x over previous
//
#include <hip/hip_runtime.h>
#include <math.h>

#define DIM 16384
#define NTH 512
#define NBLK 256

typedef float v2f __attribute__((ext_vector_type(2)));

// amp index i lives at LDS/global slot cswz(i); XOR-linear involution (bank-fold).
__host__ __device__ constexpr int cswz(int i) {
  return i ^ ((i >> 4) & 15) ^ ((i >> 8) & 15) ^ ((i >> 12) & 3);
}

// 8 passes per layer; 5 wires per window (local bit b <-> wire LW[p][b])
constexpr int LW[8][5] = {
  {13, 12, 11, 10, 0}, {10, 9, 8, 7, 6}, {6, 5, 4, 3, 2}, {2, 1, 0, 3, 4},
  {12, 13, 0, 1, 2}, {2, 3, 4, 5, 6}, {6, 7, 8, 9, 10}, {10, 11, 12, 13, 9},
};
constexpr int PMAP[8][9] = {
  {4, 5, 6, 7, 8, 9, 10, 11, 12}, {0, 1, 2, 11, 8, 9, 10, 12, 13},
  {0, 1, 2, 3, 4, 5, 6, 12, 13}, {0, 1, 2, 3, 4, 5, 6, 7, 8},
  {2, 3, 4, 5, 6, 7, 8, 9, 10}, {0, 1, 2, 3, 4, 5, 6, 12, 13},
  {0, 1, 2, 11, 8, 9, 10, 12, 13}, {5, 6, 7, 8, 9, 10, 11, 12, 13},
};
constexpr int NG[8] = {9, 8, 8, 3, 9, 8, 8, 3};
// {kind(0=RY,1=CRX), bitA(RY tgt / CRX ctrl), bitB(CRX tgt), cs index (layer-rel)}
constexpr int GATES[8][9][4] = {
  {{0,4,0,0},{0,3,0,10},{0,2,0,11},{0,1,0,12},{0,0,0,13},{1,0,4,14},{1,1,0,15},{1,2,1,16},{1,3,2,17}},
  {{0,4,0,6},{0,3,0,7},{0,2,0,8},{0,1,0,9},{1,1,0,18},{1,2,1,19},{1,3,2,20},{1,4,3,21},{0,0,0,0}},
  {{0,4,0,2},{0,3,0,3},{0,2,0,4},{0,1,0,5},{1,1,0,22},{1,2,1,23},{1,3,2,24},{1,4,3,25},{0,0,0,0}},
  {{0,1,0,1},{1,1,0,26},{1,2,1,27},{0,0,0,0},{0,0,0,0},{0,0,0,0},{0,0,0,0},{0,0,0,0},{0,0,0,0}},
  {{0,2,0,28},{0,3,0,29},{0,4,0,30},{0,0,0,40},{0,1,0,41},{1,1,0,42},{1,2,1,43},{1,3,2,44},{1,4,3,45}},
  {{0,1,0,31},{0,2,0,32},{0,3,0,33},{0,4,0,34},{1,1,0,46},{1,2,1,47},{1,3,2,48},{1,4,3,49},{0,0,0,0}},
  {{0,1,0,35},{0,2,0,36},{0,3,0,37},{0,4,0,38},{1,1,0,50},{1,2,1,51},{1,3,2,52},{1,4,3,53},{0,0,0,0}},
  {{0,1,0,39},{1,1,0,54},{1,2,1,55},{0,0,0,0},{0,0,0,0},{0,0,0,0},{0,0,0,0},{0,0,0,0},{0,0,0,0}},
};
__host__ __device__ constexpr int offcube5(int p, int j) {
  int o = 0;
  for (int b = 0; b < 5; ++b)
    if ((j >> b) & 1) o |= 1 << (13 - LW[p][b]);
  return o;
}

// MODE: 0 = gather+gates+scatter, 1 = |0>-init+gates+scatter, 2 = gather+gates (no scatter)
template <int PID, int MODE>
__device__ __forceinline__ void fb_pass(v2f* __restrict__ S, const v2f* __restrict__ CS,
                                        int lb, int tid, v2f* __restrict__ a) {
  int base = 0;
#pragma unroll
  for (int k = 0; k < 9; ++k) base |= ((tid >> k) & 1) << PMAP[PID][k];
  const int sb = cswz(base);
  if (MODE == 1) {
#pragma unroll
    for (int j = 0; j < 32; ++j) a[j] = v2f{0.f, 0.f};
    if (tid == 0) a[0] = v2f{1.f, 0.f};
  } else {
#pragma unroll
    for (int j = 0; j < 32; ++j) a[j] = S[sb ^ cswz(offcube5(PID, j))];
  }
#pragma unroll
  for (int g = 0; g < NG[PID]; ++g) {
    const v2f cs2 = CS[lb + GATES[PID][g][3]];
    const float c = cs2.x, s = cs2.y;
    if (GATES[PID][g][0] == 0) {
      const int tb = GATES[PID][g][1];
#pragma unroll
      for (int j = 0; j < 32; ++j)
        if (!((j >> tb) & 1)) {
          const int j2 = j | (1 << tb);
          const v2f a0 = a[j], a1 = a[j2];
          a[j]  = c * a0 - s * a1;
          a[j2] = s * a0 + c * a1;
        }
    } else {
      const int bc = GATES[PID][g][1], bt = GATES[PID][g][2];
#pragma unroll
      for (int j = 0; j < 32; ++j)
        if (((j >> bc) & 1) && !((j >> bt) & 1)) {
          const int j2 = j | (1 << bt);
          const v2f t0 = a[j], t1 = a[j2];
          a[j]  = c * t0 + s * v2f{t1.y, -t1.x};
          a[j2] = c * t1 + s * v2f{t0.y, -t0.x};
        }
    }
  }
  if (MODE != 2) {
#pragma unroll
    for (int j = 0; j < 32; ++j) S[sb ^ cswz(offcube5(PID, j))] = a[j];
  }
  __syncthreads();
}

// full 112-gate sim, all passes scatter; state ends in S (slot layout).
// No persistent register state — a[32] is transient per pass.
__device__ __forceinline__ void sim16(v2f* __restrict__ S, const v2f* __restrict__ CS,
                                      int tid, bool init0) {
  v2f a[32];
  if (init0) fb_pass<0, 1>(S, CS, 0, tid, a);
  else       fb_pass<0, 0>(S, CS, 0, tid, a);
  fb_pass<1, 0>(S, CS, 0, tid, a);
  fb_pass<2, 0>(S, CS, 0, tid, a);
  fb_pass<3, 0>(S, CS, 0, tid, a);
  fb_pass<4, 0>(S, CS, 0, tid, a);
  fb_pass<5, 0>(S, CS, 0, tid, a);
  fb_pass<6, 0>(S, CS, 0, tid, a);
  fb_pass<7, 0>(S, CS, 0, tid, a);
  fb_pass<0, 0>(S, CS, 56, tid, a);
  fb_pass<1, 0>(S, CS, 56, tid, a);
  fb_pass<2, 0>(S, CS, 56, tid, a);
  fb_pass<3, 0>(S, CS, 56, tid, a);
  fb_pass<4, 0>(S, CS, 56, tid, a);
  fb_pass<5, 0>(S, CS, 56, tid, a);
  fb_pass<6, 0>(S, CS, 56, tid, a);
  fb_pass<7, 0>(S, CS, 56, tid, a);
}

__device__ __forceinline__ float block_sum(float v, int tid, float* red) {
#pragma unroll
  for (int off = 32; off; off >>= 1) v += __shfl_xor(v, off);
  if ((tid & 63) == 0) red[tid >> 6] = v;
  __syncthreads();
  float tot = 0.f;
#pragma unroll
  for (int w = 0; w < 8; ++w) tot += red[w];
  __syncthreads();
  return tot;
}

__global__ __launch_bounds__(NTH, 1) void qts_kernel(
    const float* __restrict__ x, const float* __restrict__ Win,
    const float* __restrict__ bin, const float* __restrict__ mix,
    const float* __restrict__ poly, const float* __restrict__ Wout,
    const float* __restrict__ bout, float* __restrict__ out,
    v2f* __restrict__ gAall, v2f* __restrict__ gBall) {
  __shared__ v2f S[DIM + 448 + 128];
  v2f* CSall = S + DIM;
  float* red = (float*)(S + DIM + 448);
  const int tid = threadIdx.x;
  const int b = blockIdx.x;
  v2f* gA = gAall + (size_t)b * DIM;
  v2f* gB = gBall + (size_t)b * DIM;

  // angles for all 4 timesteps: theta = sigmoid(x@Win+bin); store (cos,sin)(theta/2)
  if (tid < 448) {
    float z = bin[tid];
    const float x0 = x[b * 4 + 0], x1 = x[b * 4 + 1], x2 = x[b * 4 + 2], x3 = x[b * 4 + 3];
    z += x0 * Win[tid] + x1 * Win[448 + tid] + x2 * Win[896 + tid] + x3 * Win[1344 + tid];
    const float th = 1.f / (1.f + expf(-z));
    float sn, cc;
    sincosf(0.5f * th, &sn, &cc);
    CSall[tid] = v2f{cc, sn};
  }
  __syncthreads();

  const float p0 = poly[0], p1 = poly[1], p2 = poly[2];
  float n1 = 0.f, n2 = 0.f;

  // ---- degree 0: gA = v1 = sum_t mix_t U_t(|0>) ----
  for (int t = 0; t < 4; ++t) {
    sim16(S, CSall + t * 112, tid, true);
    const float mc = mix[t];
    if (t < 3) {
#pragma unroll
      for (int j = 0; j < 32; ++j) {
        const int s = tid + j * NTH;
        gA[s] = (t == 0) ? mc * S[s] : gA[s] + mc * S[s];
      }
    } else {
      float part = 0.f;
#pragma unroll
      for (int j = 0; j < 32; ++j) {
        const int s = tid + j * NTH;
        const v2f v = gA[s] + mc * S[s];
        gA[s] = v;
        part += v.x * v.x + v.y * v.y;
      }
      n1 = sqrtf(block_sum(part, tid, red));
    }
    __syncthreads();   // S reads done before next sim scatters
  }
  const float n1e = n1 + 1e-9f;
  const float c2 = p1 / n1e;

  // ---- degree 1: gB = v2 = sum_t mix_t U_t(gA); then gA = p0*gA + c2*gB ----
  for (int t = 0; t < 4; ++t) {
#pragma unroll
    for (int j = 0; j < 32; ++j) { const int s = tid + j * NTH; S[s] = gA[s]; }
    __syncthreads();
    sim16(S, CSall + t * 112, tid, false);
    const float mc = mix[t];
    if (t < 3) {
#pragma unroll
      for (int j = 0; j < 32; ++j) {
        const int s = tid + j * NTH;
        gB[s] = (t == 0) ? mc * S[s] : gB[s] + mc * S[s];
      }
    } else {
      float part = 0.f;
#pragma unroll
      for (int j = 0; j < 32; ++j) {
        const int s = tid + j * NTH;
        const v2f v = gB[s] + mc * S[s];
        gB[s] = v;
        part += v.x * v.x + v.y * v.y;
        gA[s] = p0 * gA[s] + c2 * v;     // res partial
      }
      n2 = sqrtf(block_sum(part, tid, red));
    }
    __syncthreads();
  }
  const float n2e = n2 + 1e-9f * n1e;
  const float c3 = p2 / n2e;

  // ---- degree 2: gA += c3 * sum_t mix_t U_t(gB); final t fused with expz ----
  float part15[15];
#pragma unroll
  for (int v = 0; v < 15; ++v) part15[v] = 0.f;
  for (int t = 0; t < 4; ++t) {
#pragma unroll
    for (int j = 0; j < 32; ++j) { const int s = tid + j * NTH; S[s] = gB[s]; }
    __syncthreads();
    sim16(S, CSall + t * 112, tid, false);
    const float mc = c3 * mix[t];
    if (t < 3) {
#pragma unroll
      for (int j = 0; j < 32; ++j) {
        const int s = tid + j * NTH;
        gA[s] = gA[s] + mc * S[s];
      }
      __syncthreads();
    } else {
#pragma unroll
      for (int j = 0; j < 32; ++j) {
        const int s = tid + j * NTH;
        const v2f r = gA[s] + mc * S[s];     // final res at slot s
        const int i = cswz(s);               // amp index
        const float p = r.x * r.x + r.y * r.y;
        part15[14] += p;
#pragma unroll
        for (int w = 0; w < 14; ++w) part15[w] += ((i >> (13 - w)) & 1) ? -p : p;
      }
      __syncthreads();
    }
  }

  // ---- reduce 15 values, tiny GEMV ----
#pragma unroll
  for (int v = 0; v < 15; ++v) {
    float xv = part15[v];
#pragma unroll
    for (int off = 32; off; off >>= 1) xv += __shfl_xor(xv, off);
    if ((tid & 63) == 0) red[(tid >> 6) * 15 + v] = xv;
  }
  __syncthreads();
  if (tid < 15) {
    float tot = 0.f;
#pragma unroll
    for (int w = 0; w < 8; ++w) tot += red[w * 15 + tid];
    red[128 + tid] = tot;
  }
  __syncthreads();
  if (tid < 2) {
    const float nrm = sqrtf(red[128 + 14]) + 1e-9f;
    const float iv = 1.f / (nrm * nrm);
    float o = bout[tid];
#pragma unroll
    for (int w = 0; w < 14; ++w) o += red[128 + w] * iv * Wout[w * 2 + tid];
    out[b * 2 + tid] = o;
  }
}

// ================= fallback (verified round-6 kernel) for small ws =================
__device__ __forceinline__ void fb_sim(v2f* __restrict__ S, const v2f* __restrict__ CS,
                                       int tid, v2f* __restrict__ a,
                                       const v2f* __restrict__ basev, int own_sb,
                                       bool initzero) {
  if (initzero) {
    fb_pass<0, 1>(S, CS, 0, tid, a);
  } else {
#pragma unroll
    for (int j = 0; j < 32; ++j) S[own_sb ^ cswz(offcube5(7, j))] = basev[j];
    __syncthreads();
    fb_pass<0, 0>(S, CS, 0, tid, a);
  }
  fb_pass<1, 0>(S, CS, 0, tid, a);
  fb_pass<2, 0>(S, CS, 0, tid, a);
  fb_pass<3, 0>(S, CS, 0, tid, a);
  fb_pass<4, 0>(S, CS, 0, tid, a);
  fb_pass<5, 0>(S, CS, 0, tid, a);
  fb_pass<6, 0>(S, CS, 0, tid, a);
  fb_pass<7, 0>(S, CS, 0, tid, a);
  fb_pass<0, 0>(S, CS, 56, tid, a);
  fb_pass<1, 0>(S, CS, 56, tid, a);
  fb_pass<2, 0>(S, CS, 56, tid, a);
  fb_pass<3, 0>(S, CS, 56, tid, a);
  fb_pass<4, 0>(S, CS, 56, tid, a);
  fb_pass<5, 0>(S, CS, 56, tid, a);
  fb_pass<6, 0>(S, CS, 56, tid, a);
  fb_pass<7, 2>(S, CS, 56, tid, a);
}
__global__ __launch_bounds__(NTH, 1) void qts_fb(
    const float* __restrict__ x, const float* __restrict__ Win,
    const float* __restrict__ bin, const float* __restrict__ mix,
    const float* __restrict__ poly, const float* __restrict__ Wout,
    const float* __restrict__ bout, float* __restrict__ out) {
  __shared__ v2f S[DIM + 448 + 128];
  v2f* CSall = S + DIM;
  float* red = (float*)(S + DIM + 448);
  const int tid = threadIdx.x;
  const int b = blockIdx.x;
  if (tid < 448) {
    float z = bin[tid];
    const float x0 = x[b * 4 + 0], x1 = x[b * 4 + 1], x2 = x[b * 4 + 2], x3 = x[b * 4 + 3];
    z += x0 * Win[tid] + x1 * Win[448 + tid] + x2 * Win[896 + tid] + x3 * Win[1344 + tid];
    const float th = 1.f / (1.f + expf(-z));
    float sn, cc;
    sincosf(0.5f * th, &sn, &cc);
    CSall[tid] = v2f{cc, sn};
  }
  __syncthreads();
  int ownbase = 0;
#pragma unroll
  for (int k = 0; k < 9; ++k) ownbase |= ((tid >> k) & 1) << PMAP[7][k];
  const int own_sb = cswz(ownbase);
  const float p0 = poly[0], p1 = poly[1], p2 = poly[2];
  v2f a[32], acc[32], basev[32];
  float alpha;
#pragma unroll
  for (int j = 0; j < 32; ++j) acc[j] = v2f{0.f, 0.f};
  for (int t = 0; t < 4; ++t) {
    fb_sim(S, CSall + t * 112, tid, a, basev, own_sb, true);
    const float mc = mix[t];
#pragma unroll
    for (int j = 0; j < 32; ++j) acc[j] += mc * a[j];
  }
  {
    float part = 0.f;
#pragma unroll
    for (int j = 0; j < 32; ++j) part += acc[j].x * acc[j].x + acc[j].y * acc[j].y;
    const float tot = block_sum(part, tid, red);
    const float nu = sqrtf(tot) + 1e-9f;
    const float inv = 1.f / nu;
    alpha = p0 * nu;
#pragma unroll
    for (int j = 0; j < 32; ++j) { basev[j] = inv * acc[j]; acc[j] = v2f{0.f, 0.f}; }
  }
  for (int t = 0; t < 4; ++t) {
    fb_sim(S, CSall + t * 112, tid, a, basev, own_sb, false);
    const float mc = mix[t];
#pragma unroll
    for (int j = 0; j < 32; ++j) acc[j] += mc * a[j];
  }
  {
    float part = 0.f;
#pragma unroll
    for (int j = 0; j < 32; ++j) part += acc[j].x * acc[j].x + acc[j].y * acc[j].y;
    const float tot = block_sum(part, tid, red);
    const float nu = sqrtf(tot) + 1e-9f;
    const float inv = 1.f / nu;
#pragma unroll
    for (int j = 0; j < 32; ++j) {
      const v2f tmp = acc[j];
      acc[j] = alpha * basev[j] + p1 * tmp;
      basev[j] = inv * tmp;
    }
  }
  for (int t = 0; t < 4; ++t) {
    fb_sim(S, CSall + t * 112, tid, a, basev, own_sb, false);
    const float mc = p2 * mix[t];
#pragma unroll
    for (int j = 0; j < 32; ++j) acc[j] += mc * a[j];
  }
  float part[15];
#pragma unroll
  for (int v = 0; v < 15; ++v) part[v] = 0.f;
#pragma unroll
  for (int j = 0; j < 32; ++j) {
    const int idx = ownbase | offcube5(7, j);
    const float p = acc[j].x * acc[j].x + acc[j].y * acc[j].y;
    part[14] += p;
#pragma unroll
    for (int w = 0; w < 14; ++w) part[w] += ((idx >> (13 - w)) & 1) ? -p : p;
  }
  __syncthreads();
#pragma unroll
  for (int v = 0; v < 15; ++v) {
    float xv = part[v];
#pragma unroll
    for (int off = 32; off; off >>= 1) xv += __shfl_xor(xv, off);
    if ((tid & 63) == 0) red[(tid >> 6) * 15 + v] = xv;
  }
  __syncthreads();
  if (tid < 15) {
    float tot = 0.f;
#pragma unroll
    for (int w = 0; w < 8; ++w) tot += red[w * 15 + tid];
    red[128 + tid] = tot;
  }
  __syncthreads();
  if (tid < 2) {
    const float nrm = sqrtf(red[128 + 14]) + 1e-9f;
    const float iv = 1.f / (nrm * nrm);
    float o = bout[tid];
#pragma unroll
    for (int w = 0; w < 14; ++w) o += red[128 + w] * iv * Wout[w * 2 + tid];
    out[b * 2 + tid] = o;
  }
}

extern "C" void kernel_launch(void* const* d_in, const int* in_sizes, int n_in,
                              void* d_out, int out_size, void* d_ws, size_t ws_size,
                              hipStream_t stream) {
  const float* x    = (const float*)d_in[0];
  const float* Win  = (const float*)d_in[1];
  const float* bin  = (const float*)d_in[2];
  const float* mix  = (const float*)d_in[3];
  const float* poly = (const float*)d_in[4];
  const float* Wout = (const float*)d_in[5];
  const float* bout = (const float*)d_in[6];
  float* out = (float*)d_out;

  const size_t need = 2ull * NBLK * DIM * sizeof(float) * 2;  // 64 MB (gA + gB)
  if (ws_size >= need) {
    v2f* gA = (v2f*)d_ws;
    v2f* gB = gA + (size_t)NBLK * DIM;
    qts_kernel<<<NBLK, NTH, 0, stream>>>(x, Win, bin, mix, poly, Wout, bout, out, gA, gB);
  } else {
    qts_fb<<<NBLK, NTH, 0, stream>>>(x, Win, bin, mix, poly, Wout, bout, out);
  }
}

// Round 9
// 967.095 us; speedup vs baseline: 1.6592x; 1.2500x over previous
//
#include <hip/hip_runtime.h>
#include <math.h>

#define DIM 16384
#define NTH 512
#define NBLK 256
#define F4 (DIM / 2)   // 8192 float4 chunks (2 complex amps each)

typedef float v2f __attribute__((ext_vector_type(2)));
typedef float v4f __attribute__((ext_vector_type(4)));

// amp index i lives at LDS/global slot cswz(i); XOR-linear involution (bank-fold).
__host__ __device__ constexpr int cswz(int i) {
  return i ^ ((i >> 4) & 15) ^ ((i >> 8) & 15) ^ ((i >> 12) & 3);
}

// 8 passes per layer; 5 wires per window (local bit b <-> wire LW[p][b])
constexpr int LW[8][5] = {
  {13, 12, 11, 10, 0}, {10, 9, 8, 7, 6}, {6, 5, 4, 3, 2}, {2, 1, 0, 3, 4},
  {12, 13, 0, 1, 2}, {2, 3, 4, 5, 6}, {6, 7, 8, 9, 10}, {10, 11, 12, 13, 9},
};
constexpr int PMAP[8][9] = {
  {4, 5, 6, 7, 8, 9, 10, 11, 12}, {0, 1, 2, 11, 8, 9, 10, 12, 13},
  {0, 1, 2, 3, 4, 5, 6, 12, 13}, {0, 1, 2, 3, 4, 5, 6, 7, 8},
  {2, 3, 4, 5, 6, 7, 8, 9, 10}, {0, 1, 2, 3, 4, 5, 6, 12, 13},
  {0, 1, 2, 11, 8, 9, 10, 12, 13}, {5, 6, 7, 8, 9, 10, 11, 12, 13},
};
constexpr int NG[8] = {9, 8, 8, 3, 9, 8, 8, 3};
// {kind(0=RY,1=CRX), bitA(RY tgt / CRX ctrl), bitB(CRX tgt), cs index (layer-rel)}
constexpr int GATES[8][9][4] = {
  {{0,4,0,0},{0,3,0,10},{0,2,0,11},{0,1,0,12},{0,0,0,13},{1,0,4,14},{1,1,0,15},{1,2,1,16},{1,3,2,17}},
  {{0,4,0,6},{0,3,0,7},{0,2,0,8},{0,1,0,9},{1,1,0,18},{1,2,1,19},{1,3,2,20},{1,4,3,21},{0,0,0,0}},
  {{0,4,0,2},{0,3,0,3},{0,2,0,4},{0,1,0,5},{1,1,0,22},{1,2,1,23},{1,3,2,24},{1,4,3,25},{0,0,0,0}},
  {{0,1,0,1},{1,1,0,26},{1,2,1,27},{0,0,0,0},{0,0,0,0},{0,0,0,0},{0,0,0,0},{0,0,0,0},{0,0,0,0}},
  {{0,2,0,28},{0,3,0,29},{0,4,0,30},{0,0,0,40},{0,1,0,41},{1,1,0,42},{1,2,1,43},{1,3,2,44},{1,4,3,45}},
  {{0,1,0,31},{0,2,0,32},{0,3,0,33},{0,4,0,34},{1,1,0,46},{1,2,1,47},{1,3,2,48},{1,4,3,49},{0,0,0,0}},
  {{0,1,0,35},{0,2,0,36},{0,3,0,37},{0,4,0,38},{1,1,0,50},{1,2,1,51},{1,3,2,52},{1,4,3,53},{0,0,0,0}},
  {{0,1,0,39},{1,1,0,54},{1,2,1,55},{0,0,0,0},{0,0,0,0},{0,0,0,0},{0,0,0,0},{0,0,0,0},{0,0,0,0}},
};
__host__ __device__ constexpr int offcube5(int p, int j) {
  int o = 0;
  for (int b = 0; b < 5; ++b)
    if ((j >> b) & 1) o |= 1 << (13 - LW[p][b]);
  return o;
}

// MODE: 0 = gather+gates+scatter, 1 = |0>-init+gates+scatter, 2 = gather+gates (no scatter)
template <int PID, int MODE>
__device__ __forceinline__ void fb_pass(v2f* __restrict__ S, const v2f* __restrict__ CS,
                                        int lb, int tid, v2f* __restrict__ a) {
  int base = 0;
#pragma unroll
  for (int k = 0; k < 9; ++k) base |= ((tid >> k) & 1) << PMAP[PID][k];
  const int sb = cswz(base);
  if (MODE == 1) {
#pragma unroll
    for (int j = 0; j < 32; ++j) a[j] = v2f{0.f, 0.f};
    if (tid == 0) a[0] = v2f{1.f, 0.f};
  } else {
#pragma unroll
    for (int j = 0; j < 32; ++j) a[j] = S[sb ^ cswz(offcube5(PID, j))];
  }
#pragma unroll
  for (int g = 0; g < NG[PID]; ++g) {
    const v2f cs2 = CS[lb + GATES[PID][g][3]];
    const float c = cs2.x, s = cs2.y;
    if (GATES[PID][g][0] == 0) {
      const int tb = GATES[PID][g][1];
#pragma unroll
      for (int j = 0; j < 32; ++j)
        if (!((j >> tb) & 1)) {
          const int j2 = j | (1 << tb);
          const v2f a0 = a[j], a1 = a[j2];
          a[j]  = c * a0 - s * a1;
          a[j2] = s * a0 + c * a1;
        }
    } else {
      const int bc = GATES[PID][g][1], bt = GATES[PID][g][2];
#pragma unroll
      for (int j = 0; j < 32; ++j)
        if (((j >> bc) & 1) && !((j >> bt) & 1)) {
          const int j2 = j | (1 << bt);
          const v2f t0 = a[j], t1 = a[j2];
          a[j]  = c * t0 + s * v2f{t1.y, -t1.x};
          a[j2] = c * t1 + s * v2f{t0.y, -t0.x};
        }
    }
  }
  if (MODE != 2) {
#pragma unroll
    for (int j = 0; j < 32; ++j) S[sb ^ cswz(offcube5(PID, j))] = a[j];
  }
  __syncthreads();
}

// full 112-gate sim, all passes scatter; state ends in S (slot layout).
__device__ __forceinline__ void sim16(v2f* __restrict__ S, const v2f* __restrict__ CS,
                                      int tid, bool init0) {
  v2f a[32];
  if (init0) fb_pass<0, 1>(S, CS, 0, tid, a);
  else       fb_pass<0, 0>(S, CS, 0, tid, a);
  fb_pass<1, 0>(S, CS, 0, tid, a);
  fb_pass<2, 0>(S, CS, 0, tid, a);
  fb_pass<3, 0>(S, CS, 0, tid, a);
  fb_pass<4, 0>(S, CS, 0, tid, a);
  fb_pass<5, 0>(S, CS, 0, tid, a);
  fb_pass<6, 0>(S, CS, 0, tid, a);
  fb_pass<7, 0>(S, CS, 0, tid, a);
  fb_pass<0, 0>(S, CS, 56, tid, a);
  fb_pass<1, 0>(S, CS, 56, tid, a);
  fb_pass<2, 0>(S, CS, 56, tid, a);
  fb_pass<3, 0>(S, CS, 56, tid, a);
  fb_pass<4, 0>(S, CS, 56, tid, a);
  fb_pass<5, 0>(S, CS, 56, tid, a);
  fb_pass<6, 0>(S, CS, 56, tid, a);
  fb_pass<7, 0>(S, CS, 56, tid, a);
}

__device__ __forceinline__ float block_sum(float v, int tid, float* red) {
#pragma unroll
  for (int off = 32; off; off >>= 1) v += __shfl_xor(v, off);
  if ((tid & 63) == 0) red[tid >> 6] = v;
  __syncthreads();
  float tot = 0.f;
#pragma unroll
  for (int w = 0; w < 8; ++w) tot += red[w];
  __syncthreads();
  return tot;
}

__global__ __launch_bounds__(NTH, 1) void qts_kernel(
    const float* __restrict__ x, const float* __restrict__ Win,
    const float* __restrict__ bin, const float* __restrict__ mix,
    const float* __restrict__ poly, const float* __restrict__ Wout,
    const float* __restrict__ bout, float* __restrict__ out,
    v4f* __restrict__ gAall, v4f* __restrict__ gBall) {
  __shared__ v2f S[DIM + 448 + 128];
  v4f* SF = (v4f*)S;                       // state as 8192 float4 chunks
  v2f* CSall = S + DIM;
  float* red = (float*)(S + DIM + 448);
  const int tid = threadIdx.x;
  const int b = blockIdx.x;
  v4f* gA = gAall + (size_t)b * F4;
  v4f* gB = gBall + (size_t)b * F4;

  // angles for all 4 timesteps: theta = sigmoid(x@Win+bin); store (cos,sin)(theta/2)
  if (tid < 448) {
    float z = bin[tid];
    const float x0 = x[b * 4 + 0], x1 = x[b * 4 + 1], x2 = x[b * 4 + 2], x3 = x[b * 4 + 3];
    z += x0 * Win[tid] + x1 * Win[448 + tid] + x2 * Win[896 + tid] + x3 * Win[1344 + tid];
    const float th = 1.f / (1.f + expf(-z));
    float sn, cc;
    sincosf(0.5f * th, &sn, &cc);
    CSall[tid] = v2f{cc, sn};
  }
  __syncthreads();

  const float p0 = poly[0], p1 = poly[1], p2 = poly[2];
  float n1 = 0.f, n2 = 0.f;

  // ---- degree 0: gA = v1 = sum_t mix_t U_t(|0>); at t3 also S <- v1 ----
  for (int t = 0; t < 4; ++t) {
    sim16(S, CSall + t * 112, tid, true);
    const float mc = mix[t];
    if (t == 0) {
#pragma unroll
      for (int j = 0; j < 16; ++j) { const int f = tid + j * NTH; gA[f] = mc * SF[f]; }
    } else if (t < 3) {
#pragma unroll
      for (int j = 0; j < 16; ++j) { const int f = tid + j * NTH; gA[f] += mc * SF[f]; }
    } else {
      float part = 0.f;
#pragma unroll
      for (int j = 0; j < 16; ++j) {
        const int f = tid + j * NTH;
        const v4f v = gA[f] + mc * SF[f];
        gA[f] = v; SF[f] = v;            // S <- v1 (base for deg1 t0)
        part += v.x * v.x + v.y * v.y + v.z * v.z + v.w * v.w;
      }
      n1 = sqrtf(block_sum(part, tid, red));
    }
    __syncthreads();
  }
  const float n1e = n1 + 1e-9f;
  const float c2 = p1 / n1e;

  // ---- degree 1: gB = v2 = sum_t mix_t U_t(v1); fold res into gA; S <- v2 at t3 ----
  for (int t = 0; t < 4; ++t) {
    sim16(S, CSall + t * 112, tid, false);
    const float mc = mix[t];
    if (t == 0) {
#pragma unroll
      for (int j = 0; j < 16; ++j) {
        const int f = tid + j * NTH;
        gB[f] = mc * SF[f]; SF[f] = gA[f];   // re-init base for t1
      }
    } else if (t < 3) {
#pragma unroll
      for (int j = 0; j < 16; ++j) {
        const int f = tid + j * NTH;
        gB[f] += mc * SF[f]; SF[f] = gA[f];
      }
    } else {
      float part = 0.f;
#pragma unroll
      for (int j = 0; j < 16; ++j) {
        const int f = tid + j * NTH;
        const v4f v = gB[f] + mc * SF[f];
        gB[f] = v;
        gA[f] = p0 * gA[f] + c2 * v;         // res partial
        SF[f] = v;                           // S <- v2 (base for deg2 t0)
        part += v.x * v.x + v.y * v.y + v.z * v.z + v.w * v.w;
      }
      n2 = sqrtf(block_sum(part, tid, red));
    }
    __syncthreads();
  }
  const float n2e = n2 + 1e-9f * n1e;
  const float c3 = p2 / n2e;

  // ---- degree 2: gA += c3 * sum_t mix_t U_t(v2); final t fused with expz ----
  float part15[15];
#pragma unroll
  for (int v = 0; v < 15; ++v) part15[v] = 0.f;
  for (int t = 0; t < 4; ++t) {
    sim16(S, CSall + t * 112, tid, false);
    const float mc = c3 * mix[t];
    if (t < 3) {
#pragma unroll
      for (int j = 0; j < 16; ++j) {
        const int f = tid + j * NTH;
        gA[f] += mc * SF[f]; SF[f] = gB[f];
      }
      __syncthreads();
    } else {
#pragma unroll
      for (int j = 0; j < 16; ++j) {
        const int f = tid + j * NTH;
        const v4f r = gA[f] + mc * SF[f];    // final res (2 amps)
        const int i0 = cswz(2 * f);
        const int i1 = i0 ^ 1;               // cswz(2f+1) = cswz(2f) ^ 1
        const float pa = r.x * r.x + r.y * r.y;
        const float pb = r.z * r.z + r.w * r.w;
        part15[14] += pa + pb;
#pragma unroll
        for (int w = 0; w < 14; ++w) {
          part15[w] += ((i0 >> (13 - w)) & 1) ? -pa : pa;
          part15[w] += ((i1 >> (13 - w)) & 1) ? -pb : pb;
        }
      }
      __syncthreads();
    }
  }

  // ---- reduce 15 values, tiny GEMV ----
#pragma unroll
  for (int v = 0; v < 15; ++v) {
    float xv = part15[v];
#pragma unroll
    for (int off = 32; off; off >>= 1) xv += __shfl_xor(xv, off);
    if ((tid & 63) == 0) red[(tid >> 6) * 15 + v] = xv;
  }
  __syncthreads();
  if (tid < 15) {
    float tot = 0.f;
#pragma unroll
    for (int w = 0; w < 8; ++w) tot += red[w * 15 + tid];
    red[128 + tid] = tot;
  }
  __syncthreads();
  if (tid < 2) {
    const float nrm = sqrtf(red[128 + 14]) + 1e-9f;
    const float iv = 1.f / (nrm * nrm);
    float o = bout[tid];
#pragma unroll
    for (int w = 0; w < 14; ++w) o += red[128 + w] * iv * Wout[w * 2 + tid];
    out[b * 2 + tid] = o;
  }
}

// ================= fallback (verified round-6 kernel) for small ws =================
__device__ __forceinline__ void fb_sim(v2f* __restrict__ S, const v2f* __restrict__ CS,
                                       int tid, v2f* __restrict__ a,
                                       const v2f* __restrict__ basev, int own_sb,
                                       bool initzero) {
  if (initzero) {
    fb_pass<0, 1>(S, CS, 0, tid, a);
  } else {
#pragma unroll
    for (int j = 0; j < 32; ++j) S[own_sb ^ cswz(offcube5(7, j))] = basev[j];
    __syncthreads();
    fb_pass<0, 0>(S, CS, 0, tid, a);
  }
  fb_pass<1, 0>(S, CS, 0, tid, a);
  fb_pass<2, 0>(S, CS, 0, tid, a);
  fb_pass<3, 0>(S, CS, 0, tid, a);
  fb_pass<4, 0>(S, CS, 0, tid, a);
  fb_pass<5, 0>(S, CS, 0, tid, a);
  fb_pass<6, 0>(S, CS, 0, tid, a);
  fb_pass<7, 0>(S, CS, 0, tid, a);
  fb_pass<0, 0>(S, CS, 56, tid, a);
  fb_pass<1, 0>(S, CS, 56, tid, a);
  fb_pass<2, 0>(S, CS, 56, tid, a);
  fb_pass<3, 0>(S, CS, 56, tid, a);
  fb_pass<4, 0>(S, CS, 56, tid, a);
  fb_pass<5, 0>(S, CS, 56, tid, a);
  fb_pass<6, 0>(S, CS, 56, tid, a);
  fb_pass<7, 2>(S, CS, 56, tid, a);
}
__global__ __launch_bounds__(NTH, 1) void qts_fb(
    const float* __restrict__ x, const float* __restrict__ Win,
    const float* __restrict__ bin, const float* __restrict__ mix,
    const float* __restrict__ poly, const float* __restrict__ Wout,
    const float* __restrict__ bout, float* __restrict__ out) {
  __shared__ v2f S[DIM + 448 + 128];
  v2f* CSall = S + DIM;
  float* red = (float*)(S + DIM + 448);
  const int tid = threadIdx.x;
  const int b = blockIdx.x;
  if (tid < 448) {
    float z = bin[tid];
    const float x0 = x[b * 4 + 0], x1 = x[b * 4 + 1], x2 = x[b * 4 + 2], x3 = x[b * 4 + 3];
    z += x0 * Win[tid] + x1 * Win[448 + tid] + x2 * Win[896 + tid] + x3 * Win[1344 + tid];
    const float th = 1.f / (1.f + expf(-z));
    float sn, cc;
    sincosf(0.5f * th, &sn, &cc);
    CSall[tid] = v2f{cc, sn};
  }
  __syncthreads();
  int ownbase = 0;
#pragma unroll
  for (int k = 0; k < 9; ++k) ownbase |= ((tid >> k) & 1) << PMAP[7][k];
  const int own_sb = cswz(ownbase);
  const float p0 = poly[0], p1 = poly[1], p2 = poly[2];
  v2f a[32], acc[32], basev[32];
  float alpha;
#pragma unroll
  for (int j = 0; j < 32; ++j) acc[j] = v2f{0.f, 0.f};
  for (int t = 0; t < 4; ++t) {
    fb_sim(S, CSall + t * 112, tid, a, basev, own_sb, true);
    const float mc = mix[t];
#pragma unroll
    for (int j = 0; j < 32; ++j) acc[j] += mc * a[j];
  }
  {
    float part = 0.f;
#pragma unroll
    for (int j = 0; j < 32; ++j) part += acc[j].x * acc[j].x + acc[j].y * acc[j].y;
    const float tot = block_sum(part, tid, red);
    const float nu = sqrtf(tot) + 1e-9f;
    const float inv = 1.f / nu;
    alpha = p0 * nu;
#pragma unroll
    for (int j = 0; j < 32; ++j) { basev[j] = inv * acc[j]; acc[j] = v2f{0.f, 0.f}; }
  }
  for (int t = 0; t < 4; ++t) {
    fb_sim(S, CSall + t * 112, tid, a, basev, own_sb, false);
    const float mc = mix[t];
#pragma unroll
    for (int j = 0; j < 32; ++j) acc[j] += mc * a[j];
  }
  {
    float part = 0.f;
#pragma unroll
    for (int j = 0; j < 32; ++j) part += acc[j].x * acc[j].x + acc[j].y * acc[j].y;
    const float tot = block_sum(part, tid, red);
    const float nu = sqrtf(tot) + 1e-9f;
    const float inv = 1.f / nu;
#pragma unroll
    for (int j = 0; j < 32; ++j) {
      const v2f tmp = acc[j];
      acc[j] = alpha * basev[j] + p1 * tmp;
      basev[j] = inv * tmp;
    }
  }
  for (int t = 0; t < 4; ++t) {
    fb_sim(S, CSall + t * 112, tid, a, basev, own_sb, false);
    const float mc = p2 * mix[t];
#pragma unroll
    for (int j = 0; j < 32; ++j) acc[j] += mc * a[j];
  }
  float part[15];
#pragma unroll
  for (int v = 0; v < 15; ++v) part[v] = 0.f;
#pragma unroll
  for (int j = 0; j < 32; ++j) {
    const int idx = ownbase | offcube5(7, j);
    const float p = acc[j].x * acc[j].x + acc[j].y * acc[j].y;
    part[14] += p;
#pragma unroll
    for (int w = 0; w < 14; ++w) part[w] += ((idx >> (13 - w)) & 1) ? -p : p;
  }
  __syncthreads();
#pragma unroll
  for (int v = 0; v < 15; ++v) {
    float xv = part[v];
#pragma unroll
    for (int off = 32; off; off >>= 1) xv += __shfl_xor(xv, off);
    if ((tid & 63) == 0) red[(tid >> 6) * 15 + v] = xv;
  }
  __syncthreads();
  if (tid < 15) {
    float tot = 0.f;
#pragma unroll
    for (int w = 0; w < 8; ++w) tot += red[w * 15 + tid];
    red[128 + tid] = tot;
  }
  __syncthreads();
  if (tid < 2) {
    const float nrm = sqrtf(red[128 + 14]) + 1e-9f;
    const float iv = 1.f / (nrm * nrm);
    float o = bout[tid];
#pragma unroll
    for (int w = 0; w < 14; ++w) o += red[128 + w] * iv * Wout[w * 2 + tid];
    out[b * 2 + tid] = o;
  }
}

extern "C" void kernel_launch(void* const* d_in, const int* in_sizes, int n_in,
                              void* d_out, int out_size, void* d_ws, size_t ws_size,
                              hipStream_t stream) {
  const float* x    = (const float*)d_in[0];
  const float* Win  = (const float*)d_in[1];
  const float* bin  = (const float*)d_in[2];
  const float* mix  = (const float*)d_in[3];
  const float* poly = (const float*)d_in[4];
  const float* Wout = (const float*)d_in[5];
  const float* bout = (const float*)d_in[6];
  float* out = (float*)d_out;

  const size_t need = 2ull * NBLK * F4 * sizeof(v4f);  // 64 MB (gA + gB)
  if (ws_size >= need) {
    v4f* gA = (v4f*)d_ws;
    v4f* gB = gA + (size_t)NBLK * F4;
    qts_kernel<<<NBLK, NTH, 0, stream>>>(x, Win, bin, mix, poly, Wout, bout, out, gA, gB);
  } else {
    qts_fb<<<NBLK, NTH, 0, stream>>>(x, Win, bin, mix, poly, Wout, bout, out);
  }
}

// Round 10
// 962.624 us; speedup vs baseline: 1.6669x; 1.0046x over previous
//
#include <hip/hip_runtime.h>
#include <math.h>

#define DIM 16384
#define NTH 1024
#define NBLK 256
#define F4 (DIM / 2)      // 8192 float4 chunks
#define IT4 (F4 / NTH)    // 8 chunks per thread

typedef float v2f __attribute__((ext_vector_type(2)));
typedef float v4f __attribute__((ext_vector_type(4)));

// amp index i lives at LDS/global slot cswz(i); XOR-linear involution (bank-fold).
__host__ __device__ constexpr int cswz(int i) {
  return i ^ ((i >> 4) & 15) ^ ((i >> 8) & 15) ^ ((i >> 12) & 3);
}

// ===== main tables: 10 passes/layer, 4-wire windows (verified round 5) =====
constexpr int LWp[10][4] = {
  {13, 0, 12, 11}, {10, 9, 8, 11}, {7, 6, 5, 8}, {4, 3, 2, 5}, {1, 0, 2, 3},
  {13, 12, 0, 1}, {2, 1, 3, 4}, {5, 4, 6, 7}, {8, 7, 9, 10}, {11, 10, 12, 9},
};
// tid bit k (k=0..9) -> bit position PM[p][k] (the 10 non-window positions)
constexpr int PM[10][10] = {
  {3, 4, 5, 6, 7, 8, 9, 10, 11, 12},
  {0, 1, 6, 7, 8, 9, 10, 11, 12, 13},
  {0, 1, 2, 3, 4, 9, 10, 11, 12, 13},
  {0, 1, 2, 3, 4, 5, 6, 7, 12, 13},
  {0, 1, 2, 3, 4, 5, 6, 7, 8, 9},
  {2, 3, 4, 5, 6, 7, 8, 9, 10, 11},
  {0, 1, 2, 3, 4, 5, 6, 7, 8, 13},
  {0, 1, 2, 3, 4, 5, 10, 11, 12, 13},
  {0, 1, 2, 7, 8, 9, 10, 11, 12, 13},
  {0, 5, 6, 7, 8, 9, 10, 11, 12, 13},
};
constexpr int NGp[10] = {7, 6, 6, 6, 3, 7, 6, 6, 6, 3};
// {kind(0=RY,1=CRX), localA(RY tgt / CRX ctrl), localB(CRX tgt), cs idx (layer-rel)}
constexpr int GT[10][7][4] = {
  {{0,0,0,13},{0,1,0,0},{0,2,0,12},{0,3,0,11},{1,0,1,14},{1,2,0,15},{1,3,2,16}},
  {{0,0,0,10},{0,1,0,9},{0,2,0,8},{1,0,3,17},{1,1,0,18},{1,2,1,19},{0,0,0,0}},
  {{0,0,0,7},{0,1,0,6},{0,2,0,5},{1,0,3,20},{1,1,0,21},{1,2,1,22},{0,0,0,0}},
  {{0,0,0,4},{0,1,0,3},{0,2,0,2},{1,0,3,23},{1,1,0,24},{1,2,1,25},{0,0,0,0}},
  {{0,0,0,1},{1,0,2,26},{1,1,0,27},{0,0,0,0},{0,0,0,0},{0,0,0,0},{0,0,0,0}},
  {{0,0,0,41},{0,1,0,40},{0,2,0,28},{0,3,0,29},{1,0,1,42},{1,2,0,43},{1,3,2,44}},
  {{0,0,0,30},{0,2,0,31},{0,3,0,32},{1,0,1,45},{1,2,0,46},{1,3,2,47},{0,0,0,0}},
  {{0,0,0,33},{0,2,0,34},{0,3,0,35},{1,0,1,48},{1,2,0,49},{1,3,2,50},{0,0,0,0}},
  {{0,0,0,36},{0,2,0,37},{0,3,0,38},{1,0,1,51},{1,2,0,52},{1,3,2,53},{0,0,0,0}},
  {{0,0,0,39},{1,0,1,54},{1,2,0,55},{0,0,0,0},{0,0,0,0},{0,0,0,0},{0,0,0,0}},
};
__host__ __device__ constexpr int offcube4(int p, int j) {
  int o = 0;
  for (int b = 0; b < 4; ++b)
    if ((j >> b) & 1) o |= 1 << (13 - LWp[p][b]);
  return o;
}

// MODE: 0 = gather+gates+scatter, 1 = |0>-init+gates+scatter. Transient a[16] only.
template <int PID, int MODE>
__device__ __forceinline__ void pass16(v2f* __restrict__ S, const v2f* __restrict__ CS,
                                       int tid) {
  int base = 0;
#pragma unroll
  for (int k = 0; k < 10; ++k) base |= ((tid >> k) & 1) << PM[PID][k];
  const int sb = cswz(base);
  v2f a[16];
  if (MODE == 1) {
#pragma unroll
    for (int j = 0; j < 16; ++j) a[j] = v2f{0.f, 0.f};
    if (tid == 0) a[0] = v2f{1.f, 0.f};
  } else {
#pragma unroll
    for (int j = 0; j < 16; ++j) a[j] = S[sb ^ cswz(offcube4(PID, j))];
  }
#pragma unroll
  for (int g = 0; g < NGp[PID]; ++g) {
    const v2f cs2 = CS[GT[PID][g][3]];
    const float c = cs2.x, s = cs2.y;
    if (GT[PID][g][0] == 0) {
      const int tb = GT[PID][g][1];
#pragma unroll
      for (int j = 0; j < 16; ++j)
        if (!((j >> tb) & 1)) {
          const int j2 = j | (1 << tb);
          const v2f a0 = a[j], a1 = a[j2];
          a[j]  = c * a0 - s * a1;
          a[j2] = s * a0 + c * a1;
        }
    } else {
      const int bc = GT[PID][g][1], bt = GT[PID][g][2];
#pragma unroll
      for (int j = 0; j < 16; ++j)
        if (((j >> bc) & 1) && !((j >> bt) & 1)) {
          const int j2 = j | (1 << bt);
          const v2f t0 = a[j], t1 = a[j2];
          a[j]  = c * t0 + s * v2f{t1.y, -t1.x};
          a[j2] = c * t1 + s * v2f{t0.y, -t0.x};
        }
    }
  }
#pragma unroll
  for (int j = 0; j < 16; ++j) S[sb ^ cswz(offcube4(PID, j))] = a[j];
  __syncthreads();
}

// full 112-gate sim; state ends in S (slot layout). No persistent register state.
template <bool INIT0>
__device__ __forceinline__ void run_sim(v2f* __restrict__ S, const v2f* __restrict__ CS,
                                        int tid) {
  if (INIT0) pass16<0, 1>(S, CS, tid);
  else       pass16<0, 0>(S, CS, tid);
  pass16<1, 0>(S, CS, tid);
  pass16<2, 0>(S, CS, tid);
  pass16<3, 0>(S, CS, tid);
  pass16<4, 0>(S, CS, tid);
  pass16<5, 0>(S, CS, tid);
  pass16<6, 0>(S, CS, tid);
  pass16<7, 0>(S, CS, tid);
  pass16<8, 0>(S, CS, tid);
  pass16<9, 0>(S, CS, tid);
  const v2f* C2 = CS + 56;
  pass16<0, 0>(S, C2, tid);
  pass16<1, 0>(S, C2, tid);
  pass16<2, 0>(S, C2, tid);
  pass16<3, 0>(S, C2, tid);
  pass16<4, 0>(S, C2, tid);
  pass16<5, 0>(S, C2, tid);
  pass16<6, 0>(S, C2, tid);
  pass16<7, 0>(S, C2, tid);
  pass16<8, 0>(S, C2, tid);
  pass16<9, 0>(S, C2, tid);
}

__device__ __forceinline__ float block_sum16(float v, int tid, float* red) {
#pragma unroll
  for (int off = 32; off; off >>= 1) v += __shfl_xor(v, off);
  if ((tid & 63) == 0) red[tid >> 6] = v;
  __syncthreads();
  float tot = 0.f;
#pragma unroll
  for (int w = 0; w < 16; ++w) tot += red[w];
  __syncthreads();
  return tot;
}

__global__ __launch_bounds__(NTH, 1) void qts_kernel(
    const float* __restrict__ x, const float* __restrict__ Win,
    const float* __restrict__ bin, const float* __restrict__ mix,
    const float* __restrict__ poly, const float* __restrict__ Wout,
    const float* __restrict__ bout, float* __restrict__ out,
    v4f* __restrict__ gAall, v4f* __restrict__ gBall) {
  __shared__ v2f S[DIM + 448 + 128];
  v4f* SF = (v4f*)S;
  v2f* CSall = S + DIM;
  float* red = (float*)(S + DIM + 448);
  const int tid = threadIdx.x;
  const int b = blockIdx.x;
  v4f* gA = gAall + (size_t)b * F4;
  v4f* gB = gBall + (size_t)b * F4;

  // angles for all 4 timesteps: theta = sigmoid(x@Win+bin); store (cos,sin)(theta/2)
  if (tid < 448) {
    float z = bin[tid];
    const float x0 = x[b * 4 + 0], x1 = x[b * 4 + 1], x2 = x[b * 4 + 2], x3 = x[b * 4 + 3];
    z += x0 * Win[tid] + x1 * Win[448 + tid] + x2 * Win[896 + tid] + x3 * Win[1344 + tid];
    const float th = 1.f / (1.f + expf(-z));
    float sn, cc;
    sincosf(0.5f * th, &sn, &cc);
    CSall[tid] = v2f{cc, sn};
  }
  __syncthreads();

  const float p0 = poly[0], p1 = poly[1], p2 = poly[2];
  float n1 = 0.f, n2 = 0.f;

  // ---- degree 0: gA = v1 = sum_t mix_t U_t(|0>); at t3 also S <- v1 ----
  for (int t = 0; t < 4; ++t) {
    run_sim<true>(S, CSall + t * 112, tid);
    const float mc = mix[t];
    if (t == 0) {
#pragma unroll
      for (int j = 0; j < IT4; ++j) { const int f = tid + j * NTH; gA[f] = mc * SF[f]; }
    } else if (t < 3) {
#pragma unroll
      for (int j = 0; j < IT4; ++j) { const int f = tid + j * NTH; gA[f] += mc * SF[f]; }
    } else {
      float part = 0.f;
#pragma unroll
      for (int j = 0; j < IT4; ++j) {
        const int f = tid + j * NTH;
        const v4f v = gA[f] + mc * SF[f];
        gA[f] = v; SF[f] = v;            // S <- v1 (base for deg1 t0)
        part += v.x * v.x + v.y * v.y + v.z * v.z + v.w * v.w;
      }
      n1 = sqrtf(block_sum16(part, tid, red));
    }
    __syncthreads();
  }
  const float n1e = n1 + 1e-9f;
  const float c2 = p1 / n1e;

  // ---- degree 1: gB = v2 = sum_t mix_t U_t(v1); fold res into gA; S <- v2 at t3 ----
  for (int t = 0; t < 4; ++t) {
    run_sim<false>(S, CSall + t * 112, tid);
    const float mc = mix[t];
    if (t == 0) {
#pragma unroll
      for (int j = 0; j < IT4; ++j) {
        const int f = tid + j * NTH;
        gB[f] = mc * SF[f]; SF[f] = gA[f];
      }
    } else if (t < 3) {
#pragma unroll
      for (int j = 0; j < IT4; ++j) {
        const int f = tid + j * NTH;
        gB[f] += mc * SF[f]; SF[f] = gA[f];
      }
    } else {
      float part = 0.f;
#pragma unroll
      for (int j = 0; j < IT4; ++j) {
        const int f = tid + j * NTH;
        const v4f v = gB[f] + mc * SF[f];
        gB[f] = v;
        gA[f] = p0 * gA[f] + c2 * v;     // res partial
        SF[f] = v;                       // S <- v2 (base for deg2 t0)
        part += v.x * v.x + v.y * v.y + v.z * v.z + v.w * v.w;
      }
      n2 = sqrtf(block_sum16(part, tid, red));
    }
    __syncthreads();
  }
  const float n2e = n2 + 1e-9f * n1e;
  const float c3 = p2 / n2e;

  // ---- degree 2: gA += c3 * sum_t mix_t U_t(v2); final t fused with expz ----
  float part15[15];
#pragma unroll
  for (int v = 0; v < 15; ++v) part15[v] = 0.f;
  for (int t = 0; t < 4; ++t) {
    run_sim<false>(S, CSall + t * 112, tid);
    const float mc = c3 * mix[t];
    if (t < 3) {
#pragma unroll
      for (int j = 0; j < IT4; ++j) {
        const int f = tid + j * NTH;
        gA[f] += mc * SF[f]; SF[f] = gB[f];
      }
      __syncthreads();
    } else {
#pragma unroll
      for (int j = 0; j < IT4; ++j) {
        const int f = tid + j * NTH;
        const v4f r = gA[f] + mc * SF[f];    // final res (2 amps)
        const int i0 = cswz(2 * f);
        const int i1 = i0 ^ 1;
        const float pa = r.x * r.x + r.y * r.y;
        const float pb = r.z * r.z + r.w * r.w;
        part15[14] += pa + pb;
#pragma unroll
        for (int w = 0; w < 14; ++w) {
          part15[w] += ((i0 >> (13 - w)) & 1) ? -pa : pa;
          part15[w] += ((i1 >> (13 - w)) & 1) ? -pb : pb;
        }
      }
      __syncthreads();
    }
  }

  // ---- reduce 15 values, tiny GEMV ----
#pragma unroll
  for (int v = 0; v < 15; ++v) {
    float xv = part15[v];
#pragma unroll
    for (int off = 32; off; off >>= 1) xv += __shfl_xor(xv, off);
    if ((tid & 63) == 0) red[(tid >> 6) * 15 + v] = xv;
  }
  __syncthreads();
  if (tid < 15) {
    float tot = 0.f;
#pragma unroll
    for (int w = 0; w < 16; ++w) tot += red[w * 15 + tid];
    red[240 + tid] = tot;
  }
  __syncthreads();
  if (tid < 2) {
    const float nrm = sqrtf(red[240 + 14]) + 1e-9f;
    const float iv = 1.f / (nrm * nrm);
    float o = bout[tid];
#pragma unroll
    for (int w = 0; w < 14; ++w) o += red[240 + w] * iv * Wout[w * 2 + tid];
    out[b * 2 + tid] = o;
  }
}

// ================= fallback (verified round-6 kernel, 512 thr) for small ws =================
#define FTH 512
constexpr int LW5[8][5] = {
  {13, 12, 11, 10, 0}, {10, 9, 8, 7, 6}, {6, 5, 4, 3, 2}, {2, 1, 0, 3, 4},
  {12, 13, 0, 1, 2}, {2, 3, 4, 5, 6}, {6, 7, 8, 9, 10}, {10, 11, 12, 13, 9},
};
constexpr int PMAP5[8][9] = {
  {4, 5, 6, 7, 8, 9, 10, 11, 12}, {0, 1, 2, 11, 8, 9, 10, 12, 13},
  {0, 1, 2, 3, 4, 5, 6, 12, 13}, {0, 1, 2, 3, 4, 5, 6, 7, 8},
  {2, 3, 4, 5, 6, 7, 8, 9, 10}, {0, 1, 2, 3, 4, 5, 6, 12, 13},
  {0, 1, 2, 11, 8, 9, 10, 12, 13}, {5, 6, 7, 8, 9, 10, 11, 12, 13},
};
constexpr int NG5[8] = {9, 8, 8, 3, 9, 8, 8, 3};
constexpr int GATES5[8][9][4] = {
  {{0,4,0,0},{0,3,0,10},{0,2,0,11},{0,1,0,12},{0,0,0,13},{1,0,4,14},{1,1,0,15},{1,2,1,16},{1,3,2,17}},
  {{0,4,0,6},{0,3,0,7},{0,2,0,8},{0,1,0,9},{1,1,0,18},{1,2,1,19},{1,3,2,20},{1,4,3,21},{0,0,0,0}},
  {{0,4,0,2},{0,3,0,3},{0,2,0,4},{0,1,0,5},{1,1,0,22},{1,2,1,23},{1,3,2,24},{1,4,3,25},{0,0,0,0}},
  {{0,1,0,1},{1,1,0,26},{1,2,1,27},{0,0,0,0},{0,0,0,0},{0,0,0,0},{0,0,0,0},{0,0,0,0},{0,0,0,0}},
  {{0,2,0,28},{0,3,0,29},{0,4,0,30},{0,0,0,40},{0,1,0,41},{1,1,0,42},{1,2,1,43},{1,3,2,44},{1,4,3,45}},
  {{0,1,0,31},{0,2,0,32},{0,3,0,33},{0,4,0,34},{1,1,0,46},{1,2,1,47},{1,3,2,48},{1,4,3,49},{0,0,0,0}},
  {{0,1,0,35},{0,2,0,36},{0,3,0,37},{0,4,0,38},{1,1,0,50},{1,2,1,51},{1,3,2,52},{1,4,3,53},{0,0,0,0}},
  {{0,1,0,39},{1,1,0,54},{1,2,1,55},{0,0,0,0},{0,0,0,0},{0,0,0,0},{0,0,0,0},{0,0,0,0},{0,0,0,0}},
};
__host__ __device__ constexpr int offcube5(int p, int j) {
  int o = 0;
  for (int b = 0; b < 5; ++b)
    if ((j >> b) & 1) o |= 1 << (13 - LW5[p][b]);
  return o;
}
template <int PID, int MODE>
__device__ __forceinline__ void fb_pass(v2f* __restrict__ S, const v2f* __restrict__ CS,
                                        int lb, int tid, v2f* __restrict__ a) {
  int base = 0;
#pragma unroll
  for (int k = 0; k < 9; ++k) base |= ((tid >> k) & 1) << PMAP5[PID][k];
  const int sb = cswz(base);
  if (MODE == 1) {
#pragma unroll
    for (int j = 0; j < 32; ++j) a[j] = v2f{0.f, 0.f};
    if (tid == 0) a[0] = v2f{1.f, 0.f};
  } else {
#pragma unroll
    for (int j = 0; j < 32; ++j) a[j] = S[sb ^ cswz(offcube5(PID, j))];
  }
#pragma unroll
  for (int g = 0; g < NG5[PID]; ++g) {
    const v2f cs2 = CS[lb + GATES5[PID][g][3]];
    const float c = cs2.x, s = cs2.y;
    if (GATES5[PID][g][0] == 0) {
      const int tb = GATES5[PID][g][1];
#pragma unroll
      for (int j = 0; j < 32; ++j)
        if (!((j >> tb) & 1)) {
          const int j2 = j | (1 << tb);
          const v2f a0 = a[j], a1 = a[j2];
          a[j]  = c * a0 - s * a1;
          a[j2] = s * a0 + c * a1;
        }
    } else {
      const int bc = GATES5[PID][g][1], bt = GATES5[PID][g][2];
#pragma unroll
      for (int j = 0; j < 32; ++j)
        if (((j >> bc) & 1) && !((j >> bt) & 1)) {
          const int j2 = j | (1 << bt);
          const v2f t0 = a[j], t1 = a[j2];
          a[j]  = c * t0 + s * v2f{t1.y, -t1.x};
          a[j2] = c * t1 + s * v2f{t0.y, -t0.x};
        }
    }
  }
  if (MODE != 2) {
#pragma unroll
    for (int j = 0; j < 32; ++j) S[sb ^ cswz(offcube5(PID, j))] = a[j];
  }
  __syncthreads();
}
__device__ __forceinline__ float fb_block_sum(float v, int tid, float* red) {
#pragma unroll
  for (int off = 32; off; off >>= 1) v += __shfl_xor(v, off);
  if ((tid & 63) == 0) red[tid >> 6] = v;
  __syncthreads();
  float tot = 0.f;
#pragma unroll
  for (int w = 0; w < 8; ++w) tot += red[w];
  __syncthreads();
  return tot;
}
__device__ __forceinline__ void fb_sim(v2f* __restrict__ S, const v2f* __restrict__ CS,
                                       int tid, v2f* __restrict__ a,
                                       const v2f* __restrict__ basev, int own_sb,
                                       bool initzero) {
  if (initzero) {
    fb_pass<0, 1>(S, CS, 0, tid, a);
  } else {
#pragma unroll
    for (int j = 0; j < 32; ++j) S[own_sb ^ cswz(offcube5(7, j))] = basev[j];
    __syncthreads();
    fb_pass<0, 0>(S, CS, 0, tid, a);
  }
  fb_pass<1, 0>(S, CS, 0, tid, a);
  fb_pass<2, 0>(S, CS, 0, tid, a);
  fb_pass<3, 0>(S, CS, 0, tid, a);
  fb_pass<4, 0>(S, CS, 0, tid, a);
  fb_pass<5, 0>(S, CS, 0, tid, a);
  fb_pass<6, 0>(S, CS, 0, tid, a);
  fb_pass<7, 0>(S, CS, 0, tid, a);
  fb_pass<0, 0>(S, CS, 56, tid, a);
  fb_pass<1, 0>(S, CS, 56, tid, a);
  fb_pass<2, 0>(S, CS, 56, tid, a);
  fb_pass<3, 0>(S, CS, 56, tid, a);
  fb_pass<4, 0>(S, CS, 56, tid, a);
  fb_pass<5, 0>(S, CS, 56, tid, a);
  fb_pass<6, 0>(S, CS, 56, tid, a);
  fb_pass<7, 2>(S, CS, 56, tid, a);
}
__global__ __launch_bounds__(FTH, 1) void qts_fb(
    const float* __restrict__ x, const float* __restrict__ Win,
    const float* __restrict__ bin, const float* __restrict__ mix,
    const float* __restrict__ poly, const float* __restrict__ Wout,
    const float* __restrict__ bout, float* __restrict__ out) {
  __shared__ v2f S[DIM + 448 + 128];
  v2f* CSall = S + DIM;
  float* red = (float*)(S + DIM + 448);
  const int tid = threadIdx.x;
  const int b = blockIdx.x;
  if (tid < 448) {
    float z = bin[tid];
    const float x0 = x[b * 4 + 0], x1 = x[b * 4 + 1], x2 = x[b * 4 + 2], x3 = x[b * 4 + 3];
    z += x0 * Win[tid] + x1 * Win[448 + tid] + x2 * Win[896 + tid] + x3 * Win[1344 + tid];
    const float th = 1.f / (1.f + expf(-z));
    float sn, cc;
    sincosf(0.5f * th, &sn, &cc);
    CSall[tid] = v2f{cc, sn};
  }
  __syncthreads();
  int ownbase = 0;
#pragma unroll
  for (int k = 0; k < 9; ++k) ownbase |= ((tid >> k) & 1) << PMAP5[7][k];
  const int own_sb = cswz(ownbase);
  const float p0 = poly[0], p1 = poly[1], p2 = poly[2];
  v2f a[32], acc[32], basev[32];
  float alpha;
#pragma unroll
  for (int j = 0; j < 32; ++j) acc[j] = v2f{0.f, 0.f};
  for (int t = 0; t < 4; ++t) {
    fb_sim(S, CSall + t * 112, tid, a, basev, own_sb, true);
    const float mc = mix[t];
#pragma unroll
    for (int j = 0; j < 32; ++j) acc[j] += mc * a[j];
  }
  {
    float part = 0.f;
#pragma unroll
    for (int j = 0; j < 32; ++j) part += acc[j].x * acc[j].x + acc[j].y * acc[j].y;
    const float tot = fb_block_sum(part, tid, red);
    const float nu = sqrtf(tot) + 1e-9f;
    const float inv = 1.f / nu;
    alpha = p0 * nu;
#pragma unroll
    for (int j = 0; j < 32; ++j) { basev[j] = inv * acc[j]; acc[j] = v2f{0.f, 0.f}; }
  }
  for (int t = 0; t < 4; ++t) {
    fb_sim(S, CSall + t * 112, tid, a, basev, own_sb, false);
    const float mc = mix[t];
#pragma unroll
    for (int j = 0; j < 32; ++j) acc[j] += mc * a[j];
  }
  {
    float part = 0.f;
#pragma unroll
    for (int j = 0; j < 32; ++j) part += acc[j].x * acc[j].x + acc[j].y * acc[j].y;
    const float tot = fb_block_sum(part, tid, red);
    const float nu = sqrtf(tot) + 1e-9f;
    const float inv = 1.f / nu;
#pragma unroll
    for (int j = 0; j < 32; ++j) {
      const v2f tmp = acc[j];
      acc[j] = alpha * basev[j] + p1 * tmp;
      basev[j] = inv * tmp;
    }
  }
  for (int t = 0; t < 4; ++t) {
    fb_sim(S, CSall + t * 112, tid, a, basev, own_sb, false);
    const float mc = p2 * mix[t];
#pragma unroll
    for (int j = 0; j < 32; ++j) acc[j] += mc * a[j];
  }
  float part[15];
#pragma unroll
  for (int v = 0; v < 15; ++v) part[v] = 0.f;
#pragma unroll
  for (int j = 0; j < 32; ++j) {
    const int idx = ownbase | offcube5(7, j);
    const float p = acc[j].x * acc[j].x + acc[j].y * acc[j].y;
    part[14] += p;
#pragma unroll
    for (int w = 0; w < 14; ++w) part[w] += ((idx >> (13 - w)) & 1) ? -p : p;
  }
  __syncthreads();
#pragma unroll
  for (int v = 0; v < 15; ++v) {
    float xv = part[v];
#pragma unroll
    for (int off = 32; off; off >>= 1) xv += __shfl_xor(xv, off);
    if ((tid & 63) == 0) red[(tid >> 6) * 15 + v] = xv;
  }
  __syncthreads();
  if (tid < 15) {
    float tot = 0.f;
#pragma unroll
    for (int w = 0; w < 8; ++w) tot += red[w * 15 + tid];
    red[128 + tid] = tot;
  }
  __syncthreads();
  if (tid < 2) {
    const float nrm = sqrtf(red[128 + 14]) + 1e-9f;
    const float iv = 1.f / (nrm * nrm);
    float o = bout[tid];
#pragma unroll
    for (int w = 0; w < 14; ++w) o += red[128 + w] * iv * Wout[w * 2 + tid];
    out[b * 2 + tid] = o;
  }
}

extern "C" void kernel_launch(void* const* d_in, const int* in_sizes, int n_in,
                              void* d_out, int out_size, void* d_ws, size_t ws_size,
                              hipStream_t stream) {
  const float* x    = (const float*)d_in[0];
  const float* Win  = (const float*)d_in[1];
  const float* bin  = (const float*)d_in[2];
  const float* mix  = (const float*)d_in[3];
  const float* poly = (const float*)d_in[4];
  const float* Wout = (const float*)d_in[5];
  const float* bout = (const float*)d_in[6];
  float* out = (float*)d_out;

  const size_t need = 2ull * NBLK * F4 * sizeof(v4f);  // 64 MB (gA + gB)
  if (ws_size >= need) {
    v4f* gA = (v4f*)d_ws;
    v4f* gB = gA + (size_t)NBLK * F4;
    qts_kernel<<<NBLK, NTH, 0, stream>>>(x, Win, bin, mix, poly, Wout, bout, out, gA, gB);
  } else {
    qts_fb<<<NBLK, FTH, 0, stream>>>(x, Win, bin, mix, poly, Wout, bout, out);
  }
}